// Round 2
// baseline (184.602 us; speedup 1.0000x reference)
//
#include <hip/hip_runtime.h>
#include <hip/hip_bf16.h>

typedef unsigned short u16;
typedef __attribute__((ext_vector_type(8))) short short8;
typedef __attribute__((ext_vector_type(4))) float f32x4;

#define MFMA16(a,b,c) __builtin_amdgcn_mfma_f32_16x16x32_bf16(a,b,c,0,0,0)

__device__ __forceinline__ u16 f2bf(float x){
  union { float f; unsigned u; } v; v.f = x;
  unsigned r = v.u + 0x7FFFu + ((v.u >> 16) & 1u);   // RTNE
  return (u16)(r >> 16);
}

// ---------------- K0: W1 f32 -> bf16 (655360 elements) ----------------
__global__ void k0_cvt(const float* __restrict__ src, u16* __restrict__ dst){
  int i = (blockIdx.x * 256 + threadIdx.x) * 4;
  float4 v = *(const float4*)(src + i);
  u16 o0 = f2bf(v.x), o1 = f2bf(v.y), o2 = f2bf(v.z), o3 = f2bf(v.w);
  ushort4 o; o.x = o0; o.y = o1; o.z = o2; o.w = o3;
  *(ushort4*)(dst + i) = o;
}

// ---------------- K1: GEMM1 (bf16 MFMA) + softmax + region partial sums ----
// grid 392 (32 rows each of 12544), block 256 (4 waves)
// out: partial[blk][seg(2)][320]
__global__ __launch_bounds__(256, 2) void k1_main(
    const float* __restrict__ am, const u16* __restrict__ w1b,
    float* __restrict__ partial)
{
  __shared__ __attribute__((aligned(16))) float sL[32][320]; // 40KB; first 16KB aliased as bf16 A tile
  __shared__ __attribute__((aligned(16))) float colacc[4][640]; // 10KB
  u16* sA = (u16*)&sL[0][0];

  const int t = threadIdx.x;
  const int w = t >> 6;
  const int l = t & 63;
  const int blk = blockIdx.x;

  const f32x4 zero = {0.f, 0.f, 0.f, 0.f};
  f32x4 acc[2][5];
#pragma unroll
  for (int m = 0; m < 2; ++m)
#pragma unroll
    for (int f = 0; f < 5; ++f) acc[m][f] = zero;

  // staging mapping: 8 threads per row, 32 f32 (8 float4) per thread
  const int sr = t >> 3;
  const int sc = (t & 7) << 5;
  const float* gsrc = am + (long)(blk * 32 + sr) * 2048 + sc;

  const int llo = l & 15, lhi = l >> 4;
  const int cb = w * 80;                                   // wave's column base
  const u16* bbase = w1b + (size_t)(cb + llo) * 2048 + lhi * 8;
  const int ar0 = llo, ar1 = llo + 16;

  for (int ks = 0; ks < 8; ++ks){
    // ---- stage A chunk [32][256] f32 -> bf16 LDS (XOR-swizzled) ----
    const float4* g4 = (const float4*)(gsrc + ks * 256);
    float4 v[8];
#pragma unroll
    for (int j = 0; j < 8; ++j) v[j] = g4[j];
#pragma unroll
    for (int jj = 0; jj < 4; ++jj){
      float4 a = v[2*jj], b = v[2*jj+1];
      short8 pk;
      pk[0] = (short)f2bf(a.x); pk[1] = (short)f2bf(a.y);
      pk[2] = (short)f2bf(a.z); pk[3] = (short)f2bf(a.w);
      pk[4] = (short)f2bf(b.x); pk[5] = (short)f2bf(b.y);
      pk[6] = (short)f2bf(b.z); pk[7] = (short)f2bf(b.w);
      int byte = sr * 512 + ((sc + 8*jj) << 1);
      byte ^= (sr & 7) << 4;
      *(short8*)((char*)sA + byte) = pk;
    }
    __syncthreads();
    // ---- MFMA over BK=256 (8 k-steps of 32) ----
#pragma unroll
    for (int kk = 0; kk < 8; ++kk){
      int b0 = (ar0 * 512 + kk * 64 + lhi * 16) ^ ((ar0 & 7) << 4);
      int b1 = (ar1 * 512 + kk * 64 + lhi * 16) ^ ((ar1 & 7) << 4);
      short8 a0 = *(const short8*)((const char*)sA + b0);
      short8 a1 = *(const short8*)((const char*)sA + b1);
      const u16* bp = bbase + ks * 256 + kk * 32;
#pragma unroll
      for (int f = 0; f < 5; ++f){
        short8 bf = *(const short8*)(bp + f * 16 * 2048);
        acc[0][f] = MFMA16(a0, bf, acc[0][f]);
        acc[1][f] = MFMA16(a1, bf, acc[1][f]);
      }
    }
    __syncthreads();
  }

  // ---- dump logits to LDS (C/D map: row=(l>>4)*4+reg, col=l&15) ----
#pragma unroll
  for (int m = 0; m < 2; ++m)
#pragma unroll
    for (int f = 0; f < 5; ++f)
#pragma unroll
      for (int r = 0; r < 4; ++r)
        sL[m * 16 + lhi * 4 + r][cb + f * 16 + llo] = acc[m][f][r];
  __syncthreads();

  // ---- wave-parallel softmax over 320 cols, 8 rows per wave ----
  const int n0 = blk * 32;
  const int b_first = n0 / 196;
  float s0[5] = {0,0,0,0,0};
  float s1[5] = {0,0,0,0,0};
#pragma unroll
  for (int i = 0; i < 8; ++i){
    int rr = w * 8 + i;
    float vv[5];
#pragma unroll
    for (int j = 0; j < 5; ++j) vv[j] = sL[rr][l + 64 * j];
    float mx = vv[0];
#pragma unroll
    for (int j = 1; j < 5; ++j) mx = fmaxf(mx, vv[j]);
#pragma unroll
    for (int off = 32; off > 0; off >>= 1) mx = fmaxf(mx, __shfl_xor(mx, off));
    float e[5]; float s = 0.f;
#pragma unroll
    for (int j = 0; j < 5; ++j){ e[j] = __expf(vv[j] - mx); s += e[j]; }
#pragma unroll
    for (int off = 32; off > 0; off >>= 1) s += __shfl_xor(s, off);
    float inv = 1.f / s;
    int seg = (n0 + rr) / 196 - b_first;   // 0 or 1; wave-uniform
    if (seg == 0){
#pragma unroll
      for (int j = 0; j < 5; ++j) s0[j] += e[j] * inv;
    } else {
#pragma unroll
      for (int j = 0; j < 5; ++j) s1[j] += e[j] * inv;
    }
  }
#pragma unroll
  for (int j = 0; j < 5; ++j){
    colacc[w][l + 64 * j]       = s0[j];
    colacc[w][320 + l + 64 * j] = s1[j];
  }
  __syncthreads();
  for (int o = t; o < 640; o += 256){
    float s = colacc[0][o] + colacc[1][o] + colacc[2][o] + colacc[3][o];
    partial[blk * 640 + o] = s;
  }
}

// ---------------- K2a: reduce partials -> attr_dis (f32 ws + f32 out) ----
__global__ void k2a_reduce(const float* __restrict__ partial,
                           float* __restrict__ ad, float* __restrict__ out_ad)
{
  const int b = blockIdx.x, a = threadIdx.x;   // 64 x 320
  const int n0 = b * 196;
  const int lo = n0 >> 5, hi = (n0 + 195) >> 5;
  float s = 0.f;
  for (int blk = lo; blk <= hi; ++blk){
    int seg = b - (blk * 32) / 196;
    if (seg >= 0 && seg < 2) s += partial[blk * 640 + seg * 320 + a];
  }
  s *= (1.f / 320.f);
  ad[b * 320 + a] = s;
  out_ad[b * 320 + a] = s;
}

// ---------------- K3: features @ W3^T, f32, split-K partials ----------
// grid 256 = 16 cgroups x 16 kgroups; block 256 = 4 waves; lane = b
__global__ __launch_bounds__(256) void k3_gemm3(
    const float* __restrict__ feat, const float* __restrict__ W3,
    float* __restrict__ l3p)
{
  const int kg = blockIdx.x & 15;
  const int cg = blockIdx.x >> 4;
  const int w = threadIdx.x >> 6, b = threadIdx.x & 63;
  const float4* f4 = (const float4*)(feat + b * 2048 + kg * 128);
  float4 fr[32];
#pragma unroll
  for (int j = 0; j < 32; ++j) fr[j] = f4[j];
  const int cbase = cg * 64 + w * 16;
  for (int ci = 0; ci < 16; ++ci){
    int c = cbase + ci;
    if (c >= 1000) break;
    const float4* w4 = (const float4*)(W3 + (size_t)c * 2048 + kg * 128);
    float a0 = 0.f, a1 = 0.f, a2 = 0.f, a3 = 0.f;
#pragma unroll
    for (int j = 0; j < 32; j += 4){
      float4 x0 = fr[j],   y0 = w4[j];
      float4 x1 = fr[j+1], y1 = w4[j+1];
      float4 x2 = fr[j+2], y2 = w4[j+2];
      float4 x3 = fr[j+3], y3 = w4[j+3];
      a0 += x0.x*y0.x + x0.y*y0.y + x0.z*y0.z + x0.w*y0.w;
      a1 += x1.x*y1.x + x1.y*y1.y + x1.z*y1.z + x1.w*y1.w;
      a2 += x2.x*y2.x + x2.y*y2.y + x2.z*y2.z + x2.w*y2.w;
      a3 += x3.x*y3.x + x3.y*y3.y + x3.z*y3.z + x3.w*y3.w;
    }
    l3p[kg * 64000 + b * 1000 + c] = (a0 + a1) + (a2 + a3);
  }
}

// ---------------- K2c: attr_dis@W2^T, softmax both, combine -> f32 out ---
__global__ __launch_bounds__(256) void k2c_final(
    const float* __restrict__ ad, const float* __restrict__ W2,
    const float* __restrict__ l3p, float* __restrict__ outp)
{
  __shared__ __attribute__((aligned(16))) float sad[320];
  __shared__ float redA[4], redB[4];
  const int b = blockIdx.x, t = threadIdx.x;
  const int w = t >> 6, l = t & 63;
  for (int i = t; i < 320; i += 256) sad[i] = ad[b * 320 + i];
  __syncthreads();
  float l2v[4], l3v[4];
#pragma unroll
  for (int j = 0; j < 4; ++j){
    int c = t + 256 * j;
    if (c < 1000){
      float s3 = 0.f;
#pragma unroll
      for (int kg = 0; kg < 16; ++kg) s3 += l3p[kg * 64000 + b * 1000 + c];
      l3v[j] = s3;
      const float4* w24 = (const float4*)(W2 + (size_t)c * 320);
      const float4* a4  = (const float4*)sad;
      float s2 = 0.f;
#pragma unroll 8
      for (int i2 = 0; i2 < 80; ++i2){
        float4 x = a4[i2], y = w24[i2];
        s2 += x.x*y.x + x.y*y.y + x.z*y.z + x.w*y.w;
      }
      l2v[j] = s2;
    } else { l2v[j] = -3.4e38f; l3v[j] = -3.4e38f; }
  }
  float m2 = fmaxf(fmaxf(l2v[0], l2v[1]), fmaxf(l2v[2], l2v[3]));
  float m3 = fmaxf(fmaxf(l3v[0], l3v[1]), fmaxf(l3v[2], l3v[3]));
#pragma unroll
  for (int off = 32; off > 0; off >>= 1){
    m2 = fmaxf(m2, __shfl_xor(m2, off));
    m3 = fmaxf(m3, __shfl_xor(m3, off));
  }
  if (l == 0){ redA[w] = m2; redB[w] = m3; }
  __syncthreads();
  m2 = fmaxf(fmaxf(redA[0], redA[1]), fmaxf(redA[2], redA[3]));
  m3 = fmaxf(fmaxf(redB[0], redB[1]), fmaxf(redB[2], redB[3]));
  __syncthreads();
  float e2[4], e3[4], s2 = 0.f, s3 = 0.f;
#pragma unroll
  for (int j = 0; j < 4; ++j){
    int c = t + 256 * j;
    if (c < 1000){ e2[j] = __expf(l2v[j] - m2); e3[j] = __expf(l3v[j] - m3); }
    else         { e2[j] = 0.f; e3[j] = 0.f; }
    s2 += e2[j]; s3 += e3[j];
  }
#pragma unroll
  for (int off = 32; off > 0; off >>= 1){ s2 += __shfl_xor(s2, off); s3 += __shfl_xor(s3, off); }
  if (l == 0){ redA[w] = s2; redB[w] = s3; }
  __syncthreads();
  s2 = redA[0] + redA[1] + redA[2] + redA[3];
  s3 = redB[0] + redB[1] + redB[2] + redB[3];
  float i2 = 1.f / s2, i3 = 1.f / s3;
#pragma unroll
  for (int j = 0; j < 4; ++j){
    int c = t + 256 * j;
    if (c < 1000) outp[b * 1000 + c] = 0.5f * (e2[j] * i2 + e3[j] * i3);
  }
}

extern "C" void kernel_launch(void* const* d_in, const int* in_sizes, int n_in,
                              void* d_out, int out_size, void* d_ws, size_t ws_size,
                              hipStream_t stream)
{
  const float* attr_map = (const float*)d_in[0];
  const float* features = (const float*)d_in[1];
  const float* W1 = (const float*)d_in[2];
  const float* W2 = (const float*)d_in[3];
  const float* W3 = (const float*)d_in[4];
  float* outp = (float*)d_out;

  char* ws = (char*)d_ws;
  u16*   w1b     = (u16*)ws;                                   // 1,310,720 B
  float* partial = (float*)(ws + 1310720);                     // 1,003,520 B
  float* ad      = (float*)(ws + 1310720 + 1003520);           //    81,920 B
  float* l3p     = (float*)(ws + 1310720 + 1003520 + 81920);   // 4,096,000 B

  k0_cvt   <<<640, 256, 0, stream>>>(W1, w1b);
  k3_gemm3 <<<256, 256, 0, stream>>>(features, W3, l3p);
  k1_main  <<<392, 256, 0, stream>>>(attr_map, w1b, partial);
  k2a_reduce<<<64, 320, 0, stream>>>(partial, ad, outp + 64000);
  k2c_final<<<64, 256, 0, stream>>>(ad, W2, l3p, outp);
}

// Round 3
// 142.480 us; speedup vs baseline: 1.2956x; 1.2956x over previous
//
#include <hip/hip_runtime.h>
#include <hip/hip_bf16.h>

typedef unsigned short u16;
typedef __attribute__((ext_vector_type(8))) short short8;
typedef __attribute__((ext_vector_type(4))) float f32x4;

#define MFMA16(a,b,c) __builtin_amdgcn_mfma_f32_16x16x32_bf16(a,b,c,0,0,0)

__device__ __forceinline__ u16 f2bf(float x){
  union { float f; unsigned u; } v; v.f = x;
  unsigned r = v.u + 0x7FFFu + ((v.u >> 16) & 1u);   // RTNE
  return (u16)(r >> 16);
}

__device__ __forceinline__ void gload_lds16(const void* g, void* l){
  __builtin_amdgcn_global_load_lds(
      (const __attribute__((address_space(1))) unsigned int*)g,
      (__attribute__((address_space(3))) unsigned int*)l, 16, 0, 0);
}

// ---------------- K0: W1 f32 -> bf16 ----------------
__global__ void k0_cvt(const float* __restrict__ src, u16* __restrict__ dst){
  int i = (blockIdx.x * 256 + threadIdx.x) * 4;
  float4 v = *(const float4*)(src + i);
  ushort4 o; o.x = f2bf(v.x); o.y = f2bf(v.y); o.z = f2bf(v.z); o.w = f2bf(v.w);
  *(ushort4*)(dst + i) = o;
}

// ---------------- K0t: W2[1000][320] -> W2T[320][1024] (zero-padded) ------
__global__ void k0t_w2t(const float* __restrict__ W2, float* __restrict__ W2T){
  __shared__ float tile[32][33];
  const int t = threadIdx.x;
  const int tx = t & 31, ty = t >> 5;          // 32 x 8
  const int bx = blockIdx.x & 31;              // c tile (32 -> 1024)
  const int by = blockIdx.x >> 5;              // a tile (10 -> 320)
#pragma unroll
  for (int k = 0; k < 4; ++k){
    int c = bx*32 + ty + k*8;
    int a = by*32 + tx;
    tile[ty + k*8][tx] = (c < 1000) ? W2[(size_t)c*320 + a] : 0.f;
  }
  __syncthreads();
#pragma unroll
  for (int k = 0; k < 4; ++k){
    int a = by*32 + ty + k*8;
    int c = bx*32 + tx;
    W2T[(size_t)a*1024 + c] = tile[tx][ty + k*8];
  }
}

// ---------------- K1: GEMM1 + softmax + region partial sums ----------------
// grid 196 (64 rows each), block 256 (4 waves). out: partial[blk][2][320]
__global__ __launch_bounds__(256) void k1_main(
    const float* __restrict__ am, const u16* __restrict__ w1b,
    float* __restrict__ partial)
{
  __shared__ __attribute__((aligned(16))) u16 sB[320*64];  // 40 KB swizzled
  __shared__ __attribute__((aligned(16))) u16 sA[64*64];   //  8 KB swizzled
  __shared__ float redM[64][4];
  __shared__ float redS[64][4];

  const int t = threadIdx.x, w = t >> 6, l = t & 63;
  const int llo = l & 15, lhi = l >> 4;
  const int blk = blockIdx.x;
  const int cb = w * 80;

  const f32x4 zero = {0.f,0.f,0.f,0.f};
  f32x4 acc[4][5];
#pragma unroll
  for (int m = 0; m < 4; ++m)
#pragma unroll
    for (int f = 0; f < 5; ++f) acc[m][f] = zero;

  // A staging: thread -> row ar, 16 f32 at k-offset ac (per BK=64 slice)
  const int ar = t >> 2, ac = (t & 3) * 16;
  const float4* aptr = (const float4*)(am + (size_t)(blk*64 + ar)*2048 + ac);
  const int js0 = ((t & 3)*2)     ^ (ar & 7);
  const int js1 = ((t & 3)*2 + 1) ^ (ar & 7);
  u16* sAw0 = sA + ar*64 + js0*8;
  u16* sAw1 = sA + ar*64 + js1*8;

  // B staging: 10 chunks/thread; linear LDS dest, inverse-swizzled global src
  int boff[10]; u16* bdst[10];
#pragma unroll
  for (int p = 0; p < 10; ++p){
    int g = (p*4 + w)*64 + l;
    int row = g >> 3, j = g & 7;
    int js = j ^ (row & 7);
    boff[p] = row*2048 + js*8;
    bdst[p] = sB + g*8;
  }

  float4 av0 = aptr[0], av1 = aptr[1], av2 = aptr[2], av3 = aptr[3];

  for (int ks = 0; ks < 32; ++ks){
    // issue B(ks) -> LDS (direct DMA)
#pragma unroll
    for (int p = 0; p < 10; ++p)
      gload_lds16(w1b + boff[p] + ks*64, bdst[p]);
    // cvt + write A(ks)
    short8 p0, p1;
    p0[0]=(short)f2bf(av0.x); p0[1]=(short)f2bf(av0.y); p0[2]=(short)f2bf(av0.z); p0[3]=(short)f2bf(av0.w);
    p0[4]=(short)f2bf(av1.x); p0[5]=(short)f2bf(av1.y); p0[6]=(short)f2bf(av1.z); p0[7]=(short)f2bf(av1.w);
    p1[0]=(short)f2bf(av2.x); p1[1]=(short)f2bf(av2.y); p1[2]=(short)f2bf(av2.z); p1[3]=(short)f2bf(av2.w);
    p1[4]=(short)f2bf(av3.x); p1[5]=(short)f2bf(av3.y); p1[6]=(short)f2bf(av3.z); p1[7]=(short)f2bf(av3.w);
    *(short8*)sAw0 = p0;
    *(short8*)sAw1 = p1;
    __syncthreads();
    // prefetch A(ks+1) into regs (covered by MFMA phase)
    if (ks < 31){
      const float4* ap = aptr + (ks+1)*16;
      av0 = ap[0]; av1 = ap[1]; av2 = ap[2]; av3 = ap[3];
    }
    // MFMA over BK=64 (2 k-steps)
#pragma unroll
    for (int kk = 0; kk < 2; ++kk){
      const int jr = (((kk*4 + lhi) ^ (llo & 7))) * 8;
      short8 af[4];
#pragma unroll
      for (int m = 0; m < 4; ++m)
        af[m] = *(const short8*)(sA + (m*16 + llo)*64 + jr);
#pragma unroll
      for (int f = 0; f < 5; ++f){
        short8 bfv = *(const short8*)(sB + (cb + f*16 + llo)*64 + jr);
#pragma unroll
        for (int m = 0; m < 4; ++m)
          acc[m][f] = MFMA16(af[m], bfv, acc[m][f]);
      }
    }
    __syncthreads();
  }

  // ---- epilogue: softmax over 320 cols, rows = blk*64 + m*16 + lhi*4 + r ----
  float rmax[4][4];
#pragma unroll
  for (int m = 0; m < 4; ++m)
#pragma unroll
    for (int r = 0; r < 4; ++r){
      float x = acc[m][0][r];
#pragma unroll
      for (int f = 1; f < 5; ++f) x = fmaxf(x, acc[m][f][r]);
      x = fmaxf(x, __shfl_xor(x, 1));
      x = fmaxf(x, __shfl_xor(x, 2));
      x = fmaxf(x, __shfl_xor(x, 4));
      x = fmaxf(x, __shfl_xor(x, 8));
      rmax[m][r] = x;
    }
  if (llo == 0){
#pragma unroll
    for (int m = 0; m < 4; ++m)
#pragma unroll
      for (int r = 0; r < 4; ++r)
        redM[m*16 + lhi*4 + r][w] = rmax[m][r];
  }
  __syncthreads();
#pragma unroll
  for (int m = 0; m < 4; ++m)
#pragma unroll
    for (int r = 0; r < 4; ++r){
      int row = m*16 + lhi*4 + r;
      rmax[m][r] = fmaxf(fmaxf(redM[row][0], redM[row][1]),
                         fmaxf(redM[row][2], redM[row][3]));
    }
  // exp (in-place) + row sums
  float rsum[4][4];
#pragma unroll
  for (int m = 0; m < 4; ++m)
#pragma unroll
    for (int r = 0; r < 4; ++r){
      float s = 0.f;
#pragma unroll
      for (int f = 0; f < 5; ++f){
        float e = __expf(acc[m][f][r] - rmax[m][r]);
        acc[m][f][r] = e; s += e;
      }
      s += __shfl_xor(s, 1);
      s += __shfl_xor(s, 2);
      s += __shfl_xor(s, 4);
      s += __shfl_xor(s, 8);
      rsum[m][r] = s;
    }
  if (llo == 0){
#pragma unroll
    for (int m = 0; m < 4; ++m)
#pragma unroll
      for (int r = 0; r < 4; ++r)
        redS[m*16 + lhi*4 + r][w] = rsum[m][r];
  }
  __syncthreads();
#pragma unroll
  for (int m = 0; m < 4; ++m)
#pragma unroll
    for (int r = 0; r < 4; ++r){
      int row = m*16 + lhi*4 + r;
      rmax[m][r] = 1.f / (redS[row][0] + redS[row][1] + redS[row][2] + redS[row][3]);
    }
  // column partial sums split by b-segment
  const int n0 = blk * 64;
  const int thr = 196 * (n0/196 + 1) - n0;     // rows < thr -> seg0
  float s0[5] = {0,0,0,0,0}, s1[5] = {0,0,0,0,0};
#pragma unroll
  for (int m = 0; m < 4; ++m)
#pragma unroll
    for (int r = 0; r < 4; ++r){
      int row = m*16 + lhi*4 + r;
      float sc = rmax[m][r];
      bool in0 = row < thr;
#pragma unroll
      for (int f = 0; f < 5; ++f){
        float v = acc[m][f][r] * sc;
        s0[f] += in0 ? v : 0.f;
        s1[f] += in0 ? 0.f : v;
      }
    }
#pragma unroll
  for (int f = 0; f < 5; ++f){
    s0[f] += __shfl_xor(s0[f], 16); s0[f] += __shfl_xor(s0[f], 32);
    s1[f] += __shfl_xor(s1[f], 16); s1[f] += __shfl_xor(s1[f], 32);
  }
  if (lhi == 0){
#pragma unroll
    for (int f = 0; f < 5; ++f){
      partial[blk*640 +       cb + f*16 + llo] = s0[f];
      partial[blk*640 + 320 + cb + f*16 + llo] = s1[f];
    }
  }
}

// ---------------- K2a: reduce partials -> attr_dis -----------------------
__global__ void k2a_reduce(const float* __restrict__ partial,
                           float* __restrict__ ad, float* __restrict__ out_ad)
{
  const int b = blockIdx.x, a = threadIdx.x;   // 64 x 320
  const int lo = (196*b) >> 6, hi = (196*b + 195) >> 6;
  float s = 0.f;
  for (int blk = lo; blk <= hi; ++blk){
    int seg = b - (blk*64)/196;
    if (seg >= 0 && seg < 2) s += partial[blk*640 + seg*320 + a];
  }
  s *= (1.f / 320.f);
  ad[b*320 + a] = s;
  out_ad[b*320 + a] = s;
}

// ---------------- K3: features @ W3^T, split-K=8, padded stride 1024 ------
__global__ __launch_bounds__(256) void k3_gemm3(
    const float* __restrict__ feat, const float* __restrict__ W3,
    float* __restrict__ l3p)
{
  const int kg = blockIdx.x & 7;     // K chunk of 256
  const int cg = blockIdx.x >> 3;    // 16 c-groups of 64
  const int w = threadIdx.x >> 6, b = threadIdx.x & 63;
  const int cbase = cg*64 + w*16;
  float carr[16];
#pragma unroll
  for (int i = 0; i < 16; ++i) carr[i] = 0.f;
#pragma unroll
  for (int h = 0; h < 2; ++h){
    const float4* f4 = (const float4*)(feat + (size_t)b*2048 + kg*256 + h*128);
    float4 fr[32];
#pragma unroll
    for (int j = 0; j < 32; ++j) fr[j] = f4[j];
    for (int ci = 0; ci < 16; ++ci){
      int c = cbase + ci;
      if (c >= 1000) break;
      const float4* w4 = (const float4*)(W3 + (size_t)c*2048 + kg*256 + h*128);
      float a0=0.f, a1=0.f, a2=0.f, a3=0.f;
#pragma unroll
      for (int j = 0; j < 32; j += 4){
        float4 x0=fr[j],   y0=w4[j];
        float4 x1=fr[j+1], y1=w4[j+1];
        float4 x2=fr[j+2], y2=w4[j+2];
        float4 x3=fr[j+3], y3=w4[j+3];
        a0 += x0.x*y0.x + x0.y*y0.y + x0.z*y0.z + x0.w*y0.w;
        a1 += x1.x*y1.x + x1.y*y1.y + x1.z*y1.z + x1.w*y1.w;
        a2 += x2.x*y2.x + x2.y*y2.y + x2.z*y2.z + x2.w*y2.w;
        a3 += x3.x*y3.x + x3.y*y3.y + x3.z*y3.z + x3.w*y3.w;
      }
      carr[ci] += (a0 + a1) + (a2 + a3);
    }
  }
#pragma unroll
  for (int ci = 0; ci < 16; ++ci){
    int c = cbase + ci;
    if (c < 1000) l3p[kg*65536 + b*1024 + c] = carr[ci];
  }
}

// ---------------- K2c: attr_dis@W2T, softmax both, combine ----------------
__global__ __launch_bounds__(256) void k2c_final(
    const float* __restrict__ ad, const float* __restrict__ W2T,
    const float* __restrict__ l3p, float* __restrict__ outp)
{
  __shared__ __attribute__((aligned(16))) float sad[320];
  __shared__ float redA[4], redB[4];
  const int b = blockIdx.x, t = threadIdx.x;
  const int w = t >> 6, l = t & 63;
  for (int i = t; i < 320; i += 256) sad[i] = ad[b*320 + i];
  __syncthreads();
  const int c0 = t * 4;
  f32x4 s2v = {0.f,0.f,0.f,0.f};
  const float4* a4 = (const float4*)sad;
#pragma unroll 4
  for (int i = 0; i < 80; ++i){
    float4 sv = a4[i];
    f32x4 w0 = *(const f32x4*)(W2T + (size_t)(4*i  )*1024 + c0);
    f32x4 w1 = *(const f32x4*)(W2T + (size_t)(4*i+1)*1024 + c0);
    f32x4 w2 = *(const f32x4*)(W2T + (size_t)(4*i+2)*1024 + c0);
    f32x4 w3 = *(const f32x4*)(W2T + (size_t)(4*i+3)*1024 + c0);
    s2v += sv.x*w0 + sv.y*w1 + sv.z*w2 + sv.w*w3;
  }
  f32x4 s3v = {0.f,0.f,0.f,0.f};
#pragma unroll
  for (int kg = 0; kg < 8; ++kg)
    s3v += *(const f32x4*)(l3p + kg*65536 + b*1024 + c0);
  float l2a[4], l3a[4];
#pragma unroll
  for (int j = 0; j < 4; ++j){
    bool valid = (c0 + j) < 1000;
    l2a[j] = valid ? s2v[j] : -3.4e38f;
    l3a[j] = valid ? s3v[j] : -3.4e38f;
  }
  float m2 = fmaxf(fmaxf(l2a[0],l2a[1]), fmaxf(l2a[2],l2a[3]));
  float m3 = fmaxf(fmaxf(l3a[0],l3a[1]), fmaxf(l3a[2],l3a[3]));
#pragma unroll
  for (int off = 32; off > 0; off >>= 1){
    m2 = fmaxf(m2, __shfl_xor(m2, off));
    m3 = fmaxf(m3, __shfl_xor(m3, off));
  }
  if (l == 0){ redA[w] = m2; redB[w] = m3; }
  __syncthreads();
  m2 = fmaxf(fmaxf(redA[0],redA[1]), fmaxf(redA[2],redA[3]));
  m3 = fmaxf(fmaxf(redB[0],redB[1]), fmaxf(redB[2],redB[3]));
  __syncthreads();
  float e2[4], e3[4], s2 = 0.f, s3 = 0.f;
#pragma unroll
  for (int j = 0; j < 4; ++j){
    bool valid = (c0 + j) < 1000;
    e2[j] = valid ? __expf(l2a[j] - m2) : 0.f;
    e3[j] = valid ? __expf(l3a[j] - m3) : 0.f;
    s2 += e2[j]; s3 += e3[j];
  }
#pragma unroll
  for (int off = 32; off > 0; off >>= 1){
    s2 += __shfl_xor(s2, off);
    s3 += __shfl_xor(s3, off);
  }
  if (l == 0){ redA[w] = s2; redB[w] = s3; }
  __syncthreads();
  s2 = redA[0] + redA[1] + redA[2] + redA[3];
  s3 = redB[0] + redB[1] + redB[2] + redB[3];
  float i2 = 1.f / s2, i3 = 1.f / s3;
#pragma unroll
  for (int j = 0; j < 4; ++j){
    int c = c0 + j;
    if (c < 1000) outp[b*1000 + c] = 0.5f * (e2[j]*i2 + e3[j]*i3);
  }
}

extern "C" void kernel_launch(void* const* d_in, const int* in_sizes, int n_in,
                              void* d_out, int out_size, void* d_ws, size_t ws_size,
                              hipStream_t stream)
{
  const float* attr_map = (const float*)d_in[0];
  const float* features = (const float*)d_in[1];
  const float* W1 = (const float*)d_in[2];
  const float* W2 = (const float*)d_in[3];
  const float* W3 = (const float*)d_in[4];
  float* outp = (float*)d_out;

  char* ws = (char*)d_ws;
  u16*   w1b     = (u16*)ws;                       // 1,310,720 B
  float* W2T     = (float*)(ws + 1310720);         // 1,310,720 B
  float* partial = (float*)(ws + 2621440);         //   501,760 B
  float* ad      = (float*)(ws + 3123200);         //    81,920 B
  float* l3p     = (float*)(ws + 3205120);         // 2,097,152 B  (total 5.3 MB)

  k0_cvt    <<<640, 256, 0, stream>>>(W1, w1b);
  k1_main   <<<196, 256, 0, stream>>>(attr_map, w1b, partial);
  k0t_w2t   <<<320, 256, 0, stream>>>(W2, W2T);
  k3_gemm3  <<<128, 256, 0, stream>>>(features, W3, l3p);
  k2a_reduce<<<64, 320, 0, stream>>>(partial, ad, outp + 64000);
  k2c_final <<<64, 256, 0, stream>>>(ad, W2T, l3p, outp);
}